// Round 7
// baseline (219.255 us; speedup 1.0000x reference)
//
#include <hip/hip_runtime.h>
#include <hip/hip_bf16.h>
#include <hip/hip_cooperative_groups.h>

namespace cg = cooperative_groups;

// Problem constants
#define L_SEQ   4096
#define D_IN    1024
#define N_BATCH 16
#define L_OUT   1024
#define D_OUT   1024
#define M_DIM   (N_BATCH * L_OUT)   // 16384
#define K_DIM   D_IN

// GEMM tiling (256x256 8-phase template)
#define BM 256
#define BN 256
#define BK 64
#define NKT (K_DIM / BK)   // 16

typedef __attribute__((ext_vector_type(4))) float  f32x4;
typedef __attribute__((ext_vector_type(8))) __bf16 bf16x8;
typedef __attribute__((ext_vector_type(4))) __bf16 bf16x4;

// ws layout (bytes)
#define WS_A_OFF 0u
#define WS_W_OFF (32u * 1024u * 1024u)
#define WS_S_OFF (WS_W_OFF + 2u * 1024u * 1024u)

__device__ __forceinline__ void gload16(const __bf16* g, __bf16* l) {
    __builtin_amdgcn_global_load_lds(
        (const __attribute__((address_space(1))) void*)g,
        (__attribute__((address_space(3))) void*)l,
        16, 0, 0);
}

#define FENCE() asm volatile("" ::: "memory")

// ---------------------------------------------------------------------------
// ONE cooperative kernel, 256 blocks x 512 threads (1 block/CU):
//   phase0: blocks 0..15 compute s[b] = min(sum mask[b,:], 1024)
//   sync
//   phase1: block vb converts A panel (vb>>2) k-quarter (vb&3) + W rows vb*4..+3
//           (bf16, content-swizzled e^((row&7)<<3) within 64-elem groups)
//   fence + sync
//   phase2: 256x256 8-phase GEMM (R6 structure, T1 XCD swizzle, counted vmcnt)
// With T1 swizzle, each panel's 4 producer blocks == its 4 consumer blocks,
// all on one XCD -> A staging reads are local-L2 hits.
// ---------------------------------------------------------------------------
__global__ __launch_bounds__(512, 2) void fused_kernel(
    const float* __restrict__ x,     // (16, 4096, 1024) fp32
    const int*   __restrict__ mask,  // (16, 4096)
    const float* __restrict__ W,     // (1024, 1024) fp32
    const float* __restrict__ bias,  // (1024,)
    int*         __restrict__ s_arr, // (16,) in ws
    __bf16*      __restrict__ wsA,   // (16384, 1024) swizzled
    __bf16*      __restrict__ wsW,   // (1024, 1024) swizzled
    float*       __restrict__ out)   // (16384, 1024)
{
    __shared__ __bf16 smem[2][2][BM * BK];   // 128 KiB (GEMM); reused in phase0

    cg::grid_group grid = cg::this_grid();

    const int t  = threadIdx.x;       // 0..511
    const int bx = blockIdx.x;        // 0..255
    const int vb = (bx & 7) * 32 + (bx >> 3);  // T1 XCD-grouping swizzle

    // ================= phase 0: mask sums =================
    if (bx < N_BATCH) {
        const int4* row = (const int4*)(mask + (size_t)bx * L_SEQ); // 1024 int4
        int4 v0 = row[t];
        int4 v1 = row[t + 512];
        int sum = v0.x + v0.y + v0.z + v0.w + v1.x + v1.y + v1.z + v1.w;
#pragma unroll
        for (int off = 32; off > 0; off >>= 1) sum += __shfl_down(sum, off, 64);
        int* wsum = (int*)&smem[0][0][0];
        if ((t & 63) == 0) wsum[t >> 6] = sum;
        __syncthreads();
        if (t == 0) {
            int total = 0;
#pragma unroll
            for (int w = 0; w < 8; ++w) total += wsum[w];
            s_arr[bx] = total < L_OUT ? total : L_OUT;
        }
    }
    __threadfence();
    grid.sync();

    // ================= phase 1: convert =================
    {
        // W rows vb*4 .. vb*4+3 (4 x 1024 f32): t -> row vb*4+(t>>7), elems (t&127)*8
        const int wrow = vb * 4 + (t >> 7);
        const int we0  = (t & 127) * 8;
        const int wrsw = (wrow & 7) << 3;
        const int wdst = (we0 & ~63) | ((we0 & 63) ^ wrsw);  // 8-aligned -> contiguous 8
        f32x4 wv0 = *(const f32x4*)(W + (size_t)wrow * D_IN + we0);
        f32x4 wv1 = *(const f32x4*)(W + (size_t)wrow * D_IN + we0 + 4);
        bf16x8 wo = {(__bf16)wv0.x, (__bf16)wv0.y, (__bf16)wv0.z, (__bf16)wv0.w,
                     (__bf16)wv1.x, (__bf16)wv1.y, (__bf16)wv1.z, (__bf16)wv1.w};
        *(bf16x8*)(wsW + (size_t)wrow * K_DIM + wdst) = wo;

        // A panel quarter: panel pm=vb>>2 (rows m0..m0+255), k-cols [kq*256, +256)
        const int pm = vb >> 2;
        const int kq = vb & 3;
        const int am0 = pm * 256;
        const int b  = am0 >> 10;               // whole panel in one batch
        const int s  = s_arr[b];
        const float* xb = x + ((size_t)b * L_SEQ + (size_t)(L_SEQ - s)) * D_IN;
        const int e0 = kq * 256 + (t & 63) * 4; // 4 f32 per thread per row
        const bf16x4 zo = {(__bf16)0.f, (__bf16)0.f, (__bf16)0.f, (__bf16)0.f};
#pragma unroll 4
        for (int sweep = 0; sweep < 32; ++sweep) {
            const int rl = (t >> 6) + sweep * 8;
            const int m  = am0 + rl;
            const int j  = m & (L_OUT - 1);
            const int dste = (e0 & ~63) | ((e0 & 63) ^ ((m & 7) << 3));
            __bf16* dst = wsA + (size_t)m * K_DIM + dste;
            if (j < s) {
                f32x4 v = *(const f32x4*)(xb + (size_t)j * D_IN + e0);
                bf16x4 o = {(__bf16)v.x, (__bf16)v.y, (__bf16)v.z, (__bf16)v.w};
                *(bf16x4*)dst = o;
            } else {
                *(bf16x4*)dst = zo;
            }
        }
    }
    __threadfence();
    grid.sync();

    // ================= phase 2: GEMM =================
    const int tile_n = vb & 3;        // N/BN = 4
    const int tile_m = vb >> 2;       // M/BM = 64
    const int m0 = tile_m * BM;
    const int n0 = tile_n * BN;
    const int lane = t & 63;
    const int wave = t >> 6;
    const int wm = wave >> 2;         // 0..1
    const int wn = wave & 3;          // 0..3

    const int srow = t >> 3;          // 0..63
    const int scol = (t & 7) * 8;     // linear source elem col

    const __bf16* Ag = wsA + (size_t)m0 * K_DIM;
    const __bf16* Bg = wsW + (size_t)n0 * K_DIM;

#define STAGE_HALF(gbase, lbase, h, kt_)                                   \
    {                                                                      \
        _Pragma("unroll")                                                  \
        for (int rd = 0; rd < 2; ++rd) {                                   \
            const int r_ = (h) * 128 + rd * 64 + srow;                     \
            gload16((gbase) + (size_t)r_ * K_DIM + (kt_) * BK + scol,      \
                    (lbase) + r_ * BK + scol);                             \
        }                                                                  \
    }

    const int fr  = lane & 15;
    const int k8  = (lane >> 4) * 8;
    const int swz = (fr & 7) << 3;
    const int kc0 = k8 ^ swz;
    const int kc1 = (32 + k8) ^ swz;

    float bias_v[4];
#pragma unroll
    for (int g = 0; g < 4; ++g)
        bias_v[g] = bias[n0 + wn * 64 + g * 16 + fr];

    bf16x8 aF[4][2], bF0[2][2], bF1[2][2];
    f32x4 acc[8][4];
#pragma unroll
    for (int f = 0; f < 8; ++f)
#pragma unroll
        for (int g = 0; g < 4; ++g) acc[f][g] = (f32x4){0.f, 0.f, 0.f, 0.f};

#define LOAD_AF(Ac, mh)                                                    \
    {                                                                      \
        const __bf16* rb_ = (Ac) + (wm * 128 + (mh) * 64 + fr) * BK;       \
        _Pragma("unroll")                                                  \
        for (int i = 0; i < 4; ++i) {                                      \
            aF[i][0] = *(const bf16x8*)&rb_[i * 16 * BK + kc0];            \
            aF[i][1] = *(const bf16x8*)&rb_[i * 16 * BK + kc1];            \
        }                                                                  \
    }

#define LOAD_BF(Bc, nh, bF)                                                \
    {                                                                      \
        const __bf16* rb_ = (Bc) + (wn * 64 + (nh) * 32 + fr) * BK;        \
        _Pragma("unroll")                                                  \
        for (int j = 0; j < 2; ++j) {                                      \
            bF[j][0] = *(const bf16x8*)&rb_[j * 16 * BK + kc0];            \
            bF[j][1] = *(const bf16x8*)&rb_[j * 16 * BK + kc1];            \
        }                                                                  \
    }

#define MFMA_QUAD(mh, nh, bF)                                              \
    {                                                                      \
        _Pragma("unroll")                                                  \
        for (int i = 0; i < 4; ++i)                                        \
            _Pragma("unroll")                                              \
            for (int j = 0; j < 2; ++j) {                                  \
                f32x4 c_ = acc[(mh) * 4 + i][(nh) * 2 + j];                \
                c_ = __builtin_amdgcn_mfma_f32_16x16x32_bf16(              \
                    aF[i][0], bF[j][0], c_, 0, 0, 0);                      \
                c_ = __builtin_amdgcn_mfma_f32_16x16x32_bf16(              \
                    aF[i][1], bF[j][1], c_, 0, 0, 0);                      \
                acc[(mh) * 4 + i][(nh) * 2 + j] = c_;                      \
            }                                                              \
    }

    // prologue ledger: loads 1-8 = full buf0(kt=0); 9-12 = A(1)h0, B(1)h1
    {
        __bf16* A0l = &smem[0][0][0];
        __bf16* B0l = &smem[0][1][0];
        __bf16* A1l = &smem[1][0][0];
        __bf16* B1l = &smem[1][1][0];
        STAGE_HALF(Ag, A0l, 0, 0);
        STAGE_HALF(Bg, B0l, 1, 0);
        STAGE_HALF(Ag, A0l, 1, 0);
        STAGE_HALF(Bg, B0l, 0, 0);
        STAGE_HALF(Ag, A1l, 0, 1);
        STAGE_HALF(Bg, B1l, 1, 1);
    }

    for (int kt = 0; kt < NKT; ++kt) {
        const int cur = kt & 1;
        __bf16* Ac = &smem[cur][0][0];
        __bf16* Bc = &smem[cur][1][0];
        __bf16* An = &smem[cur ^ 1][0][0];
        __bf16* Bn = &smem[cur ^ 1][1][0];

        // ---- P1: quadrant (0,0) ----
        FENCE();
        if (kt == NKT - 1) asm volatile("s_waitcnt vmcnt(0)" ::: "memory");
        else               asm volatile("s_waitcnt vmcnt(4)" ::: "memory");
        __builtin_amdgcn_s_barrier();
        FENCE();
        LOAD_AF(Ac, 0);
        LOAD_BF(Bc, 0, bF0);
        if (kt + 1 < NKT) {
            STAGE_HALF(Ag, An, 1, kt + 1);
            STAGE_HALF(Bg, Bn, 0, kt + 1);
        }
        asm volatile("s_waitcnt lgkmcnt(0)" ::: "memory");
        __builtin_amdgcn_sched_barrier(0);
        __builtin_amdgcn_s_setprio(1);
        MFMA_QUAD(0, 0, bF0);
        __builtin_amdgcn_s_setprio(0);

        // ---- P2: quadrant (0,1) ----
        FENCE();
        __builtin_amdgcn_s_barrier();
        FENCE();
        LOAD_BF(Bc, 1, bF1);
        asm volatile("s_waitcnt lgkmcnt(0)" ::: "memory");
        __builtin_amdgcn_sched_barrier(0);
        __builtin_amdgcn_s_setprio(1);
        MFMA_QUAD(0, 1, bF1);
        __builtin_amdgcn_s_setprio(0);

        // ---- P3: quadrant (1,1) ----
        FENCE();
        __builtin_amdgcn_s_barrier();
        FENCE();
        LOAD_AF(Ac, 1);
        if (kt + 2 < NKT) STAGE_HALF(Ag, Ac, 0, kt + 2);
        asm volatile("s_waitcnt lgkmcnt(0)" ::: "memory");
        __builtin_amdgcn_sched_barrier(0);
        __builtin_amdgcn_s_setprio(1);
        MFMA_QUAD(1, 1, bF1);
        __builtin_amdgcn_s_setprio(0);

        // ---- P4: quadrant (1,0) ----
        FENCE();
        __builtin_amdgcn_s_barrier();
        FENCE();
        if (kt + 2 < NKT) STAGE_HALF(Bg, Bc, 1, kt + 2);
        __builtin_amdgcn_s_setprio(1);
        MFMA_QUAD(1, 0, bF0);
        __builtin_amdgcn_s_setprio(0);
    }

    // epilogue: bias + store
    const int row0 = m0 + wm * 128 + (lane >> 4) * 4;
    const int col0 = n0 + wn * 64 + fr;
#pragma unroll
    for (int f = 0; f < 8; ++f)
#pragma unroll
        for (int g = 0; g < 4; ++g)
#pragma unroll
            for (int rr = 0; rr < 4; ++rr)
                out[(size_t)(row0 + f * 16 + rr) * D_OUT + (col0 + g * 16)] =
                    acc[f][g][rr] + bias_v[g];

#undef STAGE_HALF
#undef LOAD_AF
#undef LOAD_BF
#undef MFMA_QUAD
}

// ---------------------------------------------------------------------------
extern "C" void kernel_launch(void* const* d_in, const int* in_sizes, int n_in,
                              void* d_out, int out_size, void* d_ws, size_t ws_size,
                              hipStream_t stream) {
    const float* x    = (const float*)d_in[0];
    const int*   mask = (const int*)d_in[1];
    const float* W    = (const float*)d_in[2];
    const float* bias = (const float*)d_in[3];
    float*       out  = (float*)d_out;

    __bf16* wsA   = (__bf16*)((char*)d_ws + WS_A_OFF);
    __bf16* wsW   = (__bf16*)((char*)d_ws + WS_W_OFF);
    int*    s_arr = (int*)((char*)d_ws + WS_S_OFF);

    void* args[] = {(void*)&x, (void*)&mask, (void*)&W, (void*)&bias,
                    (void*)&s_arr, (void*)&wsA, (void*)&wsW, (void*)&out};
    hipLaunchCooperativeKernel((const void*)fused_kernel,
                               dim3(256), dim3(512), args, 0, stream);
}

// Round 8
// 61.474 us; speedup vs baseline: 3.5666x; 3.5666x over previous
//
#include <hip/hip_runtime.h>
#include <hip/hip_bf16.h>

// Problem constants
#define L_SEQ   4096
#define D_IN    1024
#define N_BATCH 16
#define L_OUT   1024
#define D_OUT   1024
#define M_DIM   (N_BATCH * L_OUT)   // 16384
#define K_DIM   D_IN

// GEMM tiling (256x256 8-phase template)
#define BM 256
#define BN 256
#define BK 64
#define NKT (K_DIM / BK)   // 16

typedef __attribute__((ext_vector_type(4))) float  f32x4;
typedef __attribute__((ext_vector_type(8))) __bf16 bf16x8;
typedef __attribute__((ext_vector_type(4))) __bf16 bf16x4;

// ws layout (bytes)
#define WS_A_OFF 0u
#define WS_W_OFF (32u * 1024u * 1024u)
#define WS_S_OFF (WS_W_OFF + 2u * 1024u * 1024u)

// ---------------------------------------------------------------------------
// Kernel 1: s[b] = min(sum(attention_mask[b,:]), L_OUT)
// ---------------------------------------------------------------------------
__global__ __launch_bounds__(256) void mask_sum_kernel(
    const int* __restrict__ mask, int* __restrict__ s_out)
{
    const int b = blockIdx.x;
    const int t = threadIdx.x;
    const int* row = mask + (size_t)b * L_SEQ;

    int sum = 0;
#pragma unroll
    for (int i = 0; i < L_SEQ / 256; ++i) sum += row[t + i * 256];

#pragma unroll
    for (int off = 32; off > 0; off >>= 1) sum += __shfl_down(sum, off, 64);

    __shared__ int wsum[4];
    if ((t & 63) == 0) wsum[t >> 6] = sum;
    __syncthreads();
    if (t == 0) {
        int total = wsum[0] + wsum[1] + wsum[2] + wsum[3];
        s_out[b] = total < L_OUT ? total : L_OUT;
    }
}

// ---------------------------------------------------------------------------
// Kernel 2: build bf16 A (restricted+zero-padded) and bf16 W in ws,
// pre-swizzled per row: elem e -> (e & ~63) | ((e & 63) ^ ((row&7)<<3)).
// PRODUCER-XCD ALIGNMENT: A-block cb handles row rid = (cb&7)*2048 + (cb>>3),
// so the XCD that writes panel pm (rows 256pm..+255, all with rid>>11 = pm>>3)
// is the SAME XCD whose GEMM blocks (T1-swizzled, XCD = pm>>3) consume it ->
// A-staging reads become local-L2 hits. Per-XCD A slice = 4 MB = one L2.
// ---------------------------------------------------------------------------
__global__ __launch_bounds__(256) void convert_kernel(
    const float* __restrict__ x,     // (16, 4096, 1024)
    const float* __restrict__ W,     // (1024, 1024)
    const int*   __restrict__ s_arr, // (16,)
    __bf16* __restrict__ wsA,        // (16384, 1024)
    __bf16* __restrict__ wsW)        // (1024, 1024)
{
    const int cb = blockIdx.x;
    const int t  = threadIdx.x;
    const int e0 = t * 4;

    if (cb < M_DIM) {
        const int rid = (cb & 7) * 2048 + (cb >> 3);   // XCD-aligned remap
        const int b = rid >> 10;
        const int j = rid & (L_OUT - 1);
        const int s = s_arr[b];
        const int rsw  = (rid & 7) << 3;
        const int dste = (e0 & ~63) | ((e0 & 63) ^ rsw);
        __bf16* dst = wsA + (size_t)rid * K_DIM + dste;
        if (j < s) {
            const float* src = x + ((size_t)b * L_SEQ + (L_SEQ - s + j)) * D_IN + e0;
            f32x4 v = *(const f32x4*)src;
            bf16x4 o = {(__bf16)v.x, (__bf16)v.y, (__bf16)v.z, (__bf16)v.w};
            *(bf16x4*)dst = o;
        } else {
            bf16x4 o = {(__bf16)0.f, (__bf16)0.f, (__bf16)0.f, (__bf16)0.f};
            *(bf16x4*)dst = o;
        }
    } else {
        const int n = cb - M_DIM;
        const int rsw  = (n & 7) << 3;
        const int dste = (e0 & ~63) | ((e0 & 63) ^ rsw);
        const float* src = W + (size_t)n * D_IN + e0;
        f32x4 v = *(const f32x4*)src;
        bf16x4 o = {(__bf16)v.x, (__bf16)v.y, (__bf16)v.z, (__bf16)v.w};
        *(bf16x4*)(wsW + (size_t)n * K_DIM + dste) = o;
    }
}

// ---------------------------------------------------------------------------
// Kernel 3: 256x256 8-phase GEMM.  out[m,n] = sum_k A[m,k]*W[n,k] + bias[n]
// 8 waves (2M x 4N), per-wave out 128x64, acc[8][4] f32x4.
// Double-buffered LDS (128 KiB), half-tile (128x64) stage granularity,
// counted vmcnt (never 0 in steady state), setprio around MFMA clusters.
// Per-thread load ledger (verified): buf(kt) = {kt-2:P3,P4 ; kt-1:P1};
// at kt's P1 the 4 newest outstanding are kt-1:P3,P4 -> vmcnt(4) is exact.
// T1 XCD swizzle: vb=(bx&7)*32+(bx>>3) (bijective) groups the 4 tile_n
// sharers of each tile_m onto ONE XCD -> per-XCD A working set = 4MB = L2.
// ---------------------------------------------------------------------------
__device__ __forceinline__ void gload16(const __bf16* g, __bf16* l) {
    __builtin_amdgcn_global_load_lds(
        (const __attribute__((address_space(1))) void*)g,
        (__attribute__((address_space(3))) void*)l,
        16, 0, 0);
}

#define FENCE() asm volatile("" ::: "memory")

__global__ __launch_bounds__(512, 2) void gemm_kernel(
    const __bf16* __restrict__ A,    // (16384, 1024) swizzled rows
    const __bf16* __restrict__ Wb,   // (1024, 1024)  swizzled rows
    const float*  __restrict__ bias, // (1024,)
    float* __restrict__ out)         // (16384, 1024)
{
    __shared__ __bf16 smem[2][2][BM * BK];   // 128 KiB

    const int t  = threadIdx.x;       // 0..511
    const int bx = blockIdx.x;        // 256 blocks
    const int vb = (bx & 7) * 32 + (bx >> 3);  // XCD-grouping swizzle
    const int tile_n = vb & 3;        // N/BN = 4
    const int tile_m = vb >> 2;       // M/BM = 64
    const int m0 = tile_m * BM;
    const int n0 = tile_n * BN;
    const int lane = t & 63;
    const int wave = t >> 6;
    const int wm = wave >> 2;         // 0..1
    const int wn = wave & 3;          // 0..3

    // staging geometry: per gload round, 64 rows x 64 cols; LINEAR src cols
    // (ws content is already swizzled; LDS inherits the swizzled layout).
    const int srow = t >> 3;          // 0..63
    const int scol = (t & 7) * 8;     // linear source elem col
    const int sdst = (t & 7) * 8;     // linear LDS elem col

    const __bf16* Ag = A  + (size_t)m0 * K_DIM;
    const __bf16* Bg = Wb + (size_t)n0 * K_DIM;

#define STAGE_HALF(gbase, lbase, h, kt_)                                   \
    {                                                                      \
        _Pragma("unroll")                                                  \
        for (int rd = 0; rd < 2; ++rd) {                                   \
            const int r_ = (h) * 128 + rd * 64 + srow;                     \
            gload16((gbase) + (size_t)r_ * K_DIM + (kt_) * BK + scol,      \
                    (lbase) + r_ * BK + sdst);                             \
        }                                                                  \
    }

    // fragment read geometry
    const int fr  = lane & 15;
    const int k8  = (lane >> 4) * 8;
    const int swz = (fr & 7) << 3;
    const int kc0 = k8 ^ swz;
    const int kc1 = (32 + k8) ^ swz;

    // bias hoisted ahead of the K-loop (latency hidden under prologue)
    float bias_v[4];
#pragma unroll
    for (int g = 0; g < 4; ++g)
        bias_v[g] = bias[n0 + wn * 64 + g * 16 + fr];

    bf16x8 aF[4][2], bF0[2][2], bF1[2][2];
    f32x4 acc[8][4];
#pragma unroll
    for (int f = 0; f < 8; ++f)
#pragma unroll
        for (int g = 0; g < 4; ++g) acc[f][g] = (f32x4){0.f, 0.f, 0.f, 0.f};

#define LOAD_AF(Ac, mh)                                                    \
    {                                                                      \
        const __bf16* rb_ = (Ac) + (wm * 128 + (mh) * 64 + fr) * BK;       \
        _Pragma("unroll")                                                  \
        for (int i = 0; i < 4; ++i) {                                      \
            aF[i][0] = *(const bf16x8*)&rb_[i * 16 * BK + kc0];            \
            aF[i][1] = *(const bf16x8*)&rb_[i * 16 * BK + kc1];            \
        }                                                                  \
    }

#define LOAD_BF(Bc, nh, bF)                                                \
    {                                                                      \
        const __bf16* rb_ = (Bc) + (wn * 64 + (nh) * 32 + fr) * BK;        \
        _Pragma("unroll")                                                  \
        for (int j = 0; j < 2; ++j) {                                      \
            bF[j][0] = *(const bf16x8*)&rb_[j * 16 * BK + kc0];            \
            bF[j][1] = *(const bf16x8*)&rb_[j * 16 * BK + kc1];            \
        }                                                                  \
    }

#define MFMA_QUAD(mh, nh, bF)                                              \
    {                                                                      \
        _Pragma("unroll")                                                  \
        for (int i = 0; i < 4; ++i)                                        \
            _Pragma("unroll")                                              \
            for (int j = 0; j < 2; ++j) {                                  \
                f32x4 c_ = acc[(mh) * 4 + i][(nh) * 2 + j];                \
                c_ = __builtin_amdgcn_mfma_f32_16x16x32_bf16(              \
                    aF[i][0], bF[j][0], c_, 0, 0, 0);                      \
                c_ = __builtin_amdgcn_mfma_f32_16x16x32_bf16(              \
                    aF[i][1], bF[j][1], c_, 0, 0, 0);                      \
                acc[(mh) * 4 + i][(nh) * 2 + j] = c_;                      \
            }                                                              \
    }

    // prologue: A0(0), B0h1(0), A0h1... order fixes the vmcnt ledger:
    // loads 1-8 = full buf0(kt=0); 9-12 = A(1)h0, B(1)h1.
    {
        __bf16* A0l = &smem[0][0][0];
        __bf16* B0l = &smem[0][1][0];
        __bf16* A1l = &smem[1][0][0];
        __bf16* B1l = &smem[1][1][0];
        STAGE_HALF(Ag, A0l, 0, 0);
        STAGE_HALF(Bg, B0l, 1, 0);
        STAGE_HALF(Ag, A0l, 1, 0);
        STAGE_HALF(Bg, B0l, 0, 0);
        STAGE_HALF(Ag, A1l, 0, 1);
        STAGE_HALF(Bg, B1l, 1, 1);
    }

    for (int kt = 0; kt < NKT; ++kt) {
        const int cur = kt & 1;
        __bf16* Ac = &smem[cur][0][0];
        __bf16* Bc = &smem[cur][1][0];
        __bf16* An = &smem[cur ^ 1][0][0];
        __bf16* Bn = &smem[cur ^ 1][1][0];

        // ---- P1: quadrant (0,0) ----
        FENCE();
        if (kt == NKT - 1) asm volatile("s_waitcnt vmcnt(0)" ::: "memory");
        else               asm volatile("s_waitcnt vmcnt(4)" ::: "memory");
        __builtin_amdgcn_s_barrier();
        FENCE();
        LOAD_AF(Ac, 0);
        LOAD_BF(Bc, 0, bF0);
        if (kt + 1 < NKT) {
            STAGE_HALF(Ag, An, 1, kt + 1);
            STAGE_HALF(Bg, Bn, 0, kt + 1);
        }
        asm volatile("s_waitcnt lgkmcnt(0)" ::: "memory");
        __builtin_amdgcn_sched_barrier(0);
        __builtin_amdgcn_s_setprio(1);
        MFMA_QUAD(0, 0, bF0);
        __builtin_amdgcn_s_setprio(0);

        // ---- P2: quadrant (0,1) ----
        FENCE();
        __builtin_amdgcn_s_barrier();
        FENCE();
        LOAD_BF(Bc, 1, bF1);
        asm volatile("s_waitcnt lgkmcnt(0)" ::: "memory");
        __builtin_amdgcn_sched_barrier(0);
        __builtin_amdgcn_s_setprio(1);
        MFMA_QUAD(0, 1, bF1);
        __builtin_amdgcn_s_setprio(0);

        // ---- P3: quadrant (1,1) ----
        FENCE();
        __builtin_amdgcn_s_barrier();
        FENCE();
        LOAD_AF(Ac, 1);
        if (kt + 2 < NKT) STAGE_HALF(Ag, Ac, 0, kt + 2);
        asm volatile("s_waitcnt lgkmcnt(0)" ::: "memory");
        __builtin_amdgcn_sched_barrier(0);
        __builtin_amdgcn_s_setprio(1);
        MFMA_QUAD(1, 1, bF1);
        __builtin_amdgcn_s_setprio(0);

        // ---- P4: quadrant (1,0) ----
        FENCE();
        __builtin_amdgcn_s_barrier();
        FENCE();
        if (kt + 2 < NKT) STAGE_HALF(Bg, Bc, 1, kt + 2);
        __builtin_amdgcn_s_setprio(1);
        MFMA_QUAD(1, 0, bF0);
        __builtin_amdgcn_s_setprio(0);
    }

    // epilogue: bias + store
    const int row0 = m0 + wm * 128 + (lane >> 4) * 4;
    const int col0 = n0 + wn * 64 + fr;
#pragma unroll
    for (int f = 0; f < 8; ++f)
#pragma unroll
        for (int g = 0; g < 4; ++g)
#pragma unroll
            for (int rr = 0; rr < 4; ++rr)
                out[(size_t)(row0 + f * 16 + rr) * D_OUT + (col0 + g * 16)] =
                    acc[f][g][rr] + bias_v[g];

#undef STAGE_HALF
#undef LOAD_AF
#undef LOAD_BF
#undef MFMA_QUAD
}

// ---------------------------------------------------------------------------
extern "C" void kernel_launch(void* const* d_in, const int* in_sizes, int n_in,
                              void* d_out, int out_size, void* d_ws, size_t ws_size,
                              hipStream_t stream) {
    const float* x    = (const float*)d_in[0];
    const int*   mask = (const int*)d_in[1];
    const float* W    = (const float*)d_in[2];
    const float* bias = (const float*)d_in[3];
    float*       out  = (float*)d_out;

    __bf16* wsA   = (__bf16*)((char*)d_ws + WS_A_OFF);
    __bf16* wsW   = (__bf16*)((char*)d_ws + WS_W_OFF);
    int*    s_arr = (int*)((char*)d_ws + WS_S_OFF);

    mask_sum_kernel<<<dim3(N_BATCH), dim3(256), 0, stream>>>(mask, s_arr);

    convert_kernel<<<dim3(M_DIM + D_OUT), dim3(256), 0, stream>>>(
        x, W, s_arr, wsA, wsW);

    const int grid = (M_DIM / BM) * (D_OUT / BN);  // 64 * 4 = 256
    gemm_kernel<<<dim3(grid), dim3(512), 0, stream>>>(wsA, wsW, bias, out);
}